// Round 11
// baseline (159.382 us; speedup 1.0000x reference)
//
#include <hip/hip_runtime.h>
#include <hip/hip_bf16.h>

// ---------------------------------------------------------------------------
// DimNet via bf16 MFMA implicit GEMM.
//   Pn  = padded input  NHWC bf16 [2][104][104][32]
//   Bn  = relu(conv2a)  NHWC bf16 [2][100][100][192] (g' = uv*20+mc)
//   Wp  = packed main weights [231 steps][ocb7][frag4][lane64][8] bf16
//   Wc2 = packed conv2a weights [ocb6][tap25][slot128][8] bf16
// K1 prep1: pad (85 blk) + conv2a weight pack (6 blk)
// K2 conv2a_fused: Wp transposes (63 blk, LDS-staged, 16-oc passes) + conv2a
//   MFMA (624 blk) in ONE grid -> transpose cost hides under conv2a.
// K3 conv_mfma: EXACT round-7/10 kernel (anchor: 102us / 52% MfmaUtil).
// ---------------------------------------------------------------------------

typedef __attribute__((ext_vector_type(8))) unsigned short ushort8;
typedef __attribute__((ext_vector_type(8))) __bf16 bf16x8;
typedef __attribute__((ext_vector_type(4))) float f32x4;

#define NB 2
#define HSLOT 576             // cells per k-slot (16 rows x 36 cols)
#define HBUF (4 * HSLOT * 8)  // ushorts per halo buffer = 18432
#define WST 14336             // ushorts per step in packed weights (7*4*64*8)

static __device__ __forceinline__ unsigned short f2bf(float f) {
    __hip_bfloat16 h = __float2bfloat16(f);
    return *reinterpret_cast<unsigned short*>(&h);
}
static __device__ __forceinline__ void gload16(const unsigned short* g, unsigned short* l) {
    __builtin_amdgcn_global_load_lds(
        (const __attribute__((address_space(1))) unsigned int*)(const void*)g,
        (__attribute__((address_space(3))) unsigned int*)(void*)l, 16, 0, 0);
}

// ---------------- K1: pad + conv2a weight pack ----------------
__global__ __launch_bounds__(256) void prep1_kernel(
    const float* __restrict__ pic, const float* __restrict__ w2a,
    unsigned short* __restrict__ Pn, unsigned short* __restrict__ Wc2) {
    const int blk = blockIdx.x;
    const int tid = threadIdx.x;
    if (blk < 85) {
        int idx = blk * 256 + tid;
        if (idx >= NB * 104 * 104) return;
        int x = idx % 104;
        int y = (idx / 104) % 104;
        int b = idx / (104 * 104);
        unsigned short vals[32];
        bool inter = (y >= 4 && y < 100 && x >= 4 && x < 100);
#pragma unroll
        for (int c = 0; c < 25; ++c) {
            float v = inter ? pic[((b * 25 + c) * 96 + (y - 4)) * 96 + (x - 4)] : 0.5f;
            vals[c] = f2bf(v);
        }
#pragma unroll
        for (int c = 25; c < 32; ++c) vals[c] = 0;
        ushort8* dst = (ushort8*)(Pn + idx * 32);
#pragma unroll
        for (int j = 0; j < 4; ++j) dst[j] = *(ushort8*)&vals[j * 8];
    } else {
        // conv2a weight pack: block = ocB2 (32 oc), threads 0..127
        int ocB2 = blk - 85;
        if (tid < 128) {
            int lane = tid & 63;
            int oc = ocB2 * 32 + (tid >> 6) * 16 + (lane & 15);
            int kb = (lane >> 4) * 8;
            int uv = oc / 20, mc = oc % 20;
            int u = uv / 3, v = uv % 3;
            const float* wb[8];
#pragma unroll
            for (int e = 0; e < 8; ++e) {
                int k  = kb + e;
                int c1 = k / 5, c2 = k % 5;
                int da1 = c1 - u, da2 = c2 - v;
                bool valid = (oc < 180) && ((unsigned)da1 < 3u) && ((unsigned)da2 < 3u);
                wb[e] = valid ? (w2a + mc * 225 + (da1 * 3 + da2) * 25) : (const float*)0;
            }
            for (int tap = 0; tap < 25; ++tap) {
                unsigned short fr[8];
#pragma unroll
                for (int e = 0; e < 8; ++e) fr[e] = wb[e] ? f2bf(wb[e][tap]) : (unsigned short)0;
                *(ushort8*)(Wc2 + ((size_t)(ocB2 * 25 + tap) * 128 + tid) * 8) = *(ushort8*)fr;
            }
        }
    }
}

// ---------------- K2: Wp transposes + conv2a MFMA in one grid ----------------
__global__ __launch_bounds__(256) void conv2a_fused_kernel(
    const unsigned short* __restrict__ Pn, const unsigned short* __restrict__ Wc2,
    const float* __restrict__ b2a, const float* __restrict__ w1,
    const float* __restrict__ w2b, unsigned short* __restrict__ Bn,
    unsigned short* __restrict__ Wp) {
    __shared__ __align__(16) unsigned short sMem[14336];  // 28,672 B (halo / sT union)
    const int bx  = blockIdx.x;
    const int tid = threadIdx.x;

    if (bx < 42) {
        // ---- w2b transpose: block (ocB, cc), four 16-oc passes ----
        int ocB = bx % 7, cc = bx / 7;
        for (int n32 = 0; n32 < 4; ++n32) {
            if (n32) __syncthreads();
#pragma unroll
            for (int j = 0; j < 2; ++j) {
                int p  = tid * 2 + j;          // 0..511
                int gl = p >> 4, ol = p & 15;  // gl: k-in-chunk 0..31
                int oc = ocB * 64 + n32 * 16 + ol;
                int gp = cc * 32 + gl;
                const float* src = nullptr;
                if (oc < 400 && gp < 180) {
                    int mc = gp % 20, uv = gp / 20;   // g' = uv*20 + mc
                    src = w2b + oc * 4500 + (mc * 9 + uv) * 25;
                }
                for (int tap = 0; tap < 25; ++tap)
                    sMem[(gl * 25 + tap) * 17 + ol] = src ? f2bf(src[tap]) : (unsigned short)0;
            }
            __syncthreads();
            for (int i = 0; i < 7; ++i) {
                int sid = i * 256 + tid;
                if (sid < 1600) {
                    int tap = sid >> 6, lane = sid & 63;
                    int kq = lane >> 4, l15 = lane & 15;
                    unsigned short v8[8];
#pragma unroll
                    for (int e = 0; e < 8; ++e)
                        v8[e] = sMem[((kq * 8 + e) * 25 + tap) * 17 + l15];
                    size_t d = (size_t)(cc * 25 + tap) * WST + ocB * 2048 + n32 * 512 + lane * 8;
                    *(ushort8*)(Wp + d) = *(ushort8*)v8;
                }
            }
        }
    } else if (bx < 63) {
        // ---- w1 transpose: block (ocB, tap-third), four 16-oc passes ----
        int b3 = bx - 42;
        int ocB = b3 % 7, tt = b3 / 7;  // tt 0..2 -> linear taps tt*27..+26
        for (int n32 = 0; n32 < 4; ++n32) {
            if (n32) __syncthreads();
#pragma unroll
            for (int j = 0; j < 2; ++j) {
                int p  = tid * 2 + j;
                int cl = p >> 4, ol = p & 15;
                if (cl < 25) {
                    int oc = ocB * 64 + n32 * 16 + ol;
                    const float* src = (oc < 400) ? (w1 + oc * 2025 + cl * 81 + tt * 27)
                                                  : (const float*)0;
                    for (int tl = 0; tl < 27; ++tl)
                        sMem[(cl * 27 + tl) * 17 + ol] = src ? f2bf(src[tl]) : (unsigned short)0;
                }
            }
            __syncthreads();
            for (int i = 0; i < 7; ++i) {
                int sid = i * 256 + tid;
                if (sid < 1728) {
                    int tl = sid >> 6, lane = sid & 63;
                    int kq = lane >> 4, l15 = lane & 15;
                    unsigned short v8[8];
#pragma unroll
                    for (int e = 0; e < 8; ++e) {
                        int k = kq * 8 + e;
                        v8[e] = (k < 25) ? sMem[(k * 27 + tl) * 17 + l15] : (unsigned short)0;
                    }
                    int tap_lin = tt * 27 + tl;
                    int dy = tap_lin / 9, dx = tap_lin % 9;
                    int tp = (dx < 5) ? (dy * 5 + dx) : (45 + dy * 4 + (dx - 5));
                    size_t d = (size_t)(150 + tp) * WST + ocB * 2048 + n32 * 512 + lane * 8;
                    *(ushort8*)(Wp + d) = *(ushort8*)v8;
                }
            }
        }
    } else {
        // ---- conv2a MFMA: cid = bx-63, 256px x 32oc ----
        int cid = bx - 63;
        const int lane = tid & 63, w = tid >> 6;
        const int l15  = lane & 15, lhi = lane >> 4;
        const int gx0  = cid % 104;
        const int ocB  = cid / 104;
        const int b    = gx0 / 52, t52 = gx0 % 52;
        const int ty0  = (t52 >> 2) * 8;
        const int tx0  = (t52 & 3) * 32;

        for (int L2 = 0; L2 < 7; ++L2) {
            int p = L2 * 64 + lane;
            if (p >= 432) p = 0;
            int hy = (p * 58255) >> 21, hx = p - hy * 36;
            int gy = ty0 + hy; gy = gy > 103 ? 103 : gy;
            int gx = tx0 + hx; gx = gx > 103 ? 103 : gx;
            gload16(Pn + ((size_t)((b * 104 + gy) * 104 + gx)) * 32 + w * 8,
                    &sMem[(w * 448 + L2 * 64) * 8]);
        }
        float bs[2];
#pragma unroll
        for (int n = 0; n < 2; ++n) {
            int oc = ocB * 32 + n * 16 + l15;
            bs[n] = (oc < 180) ? b2a[oc % 20] : 0.f;
        }
        __syncthreads();

        const unsigned short* hb = &sMem[(lhi * 448 + w * 72 + l15) * 8];
        const unsigned short* wq = Wc2 + (size_t)ocB * 25600 + lane * 8;

        f32x4 acc[4][2] = {};
#pragma unroll
        for (int t = 0; t < 25; ++t) {
            const int u = ((t / 5) * 36 + (t % 5)) * 8;
            bf16x8 a0 = *(const bf16x8*)(hb + u);
            bf16x8 a1 = *(const bf16x8*)(hb + u + 128);
            bf16x8 a2 = *(const bf16x8*)(hb + u + 288);
            bf16x8 a3 = *(const bf16x8*)(hb + u + 416);
            bf16x8 c0 = *(const bf16x8*)(wq);
            bf16x8 c1 = *(const bf16x8*)(wq + 512);
            __builtin_amdgcn_s_setprio(1);
            acc[0][0] = __builtin_amdgcn_mfma_f32_16x16x32_bf16(a0, c0, acc[0][0], 0, 0, 0);
            acc[0][1] = __builtin_amdgcn_mfma_f32_16x16x32_bf16(a0, c1, acc[0][1], 0, 0, 0);
            acc[1][0] = __builtin_amdgcn_mfma_f32_16x16x32_bf16(a1, c0, acc[1][0], 0, 0, 0);
            acc[1][1] = __builtin_amdgcn_mfma_f32_16x16x32_bf16(a1, c1, acc[1][1], 0, 0, 0);
            acc[2][0] = __builtin_amdgcn_mfma_f32_16x16x32_bf16(a2, c0, acc[2][0], 0, 0, 0);
            acc[2][1] = __builtin_amdgcn_mfma_f32_16x16x32_bf16(a2, c1, acc[2][1], 0, 0, 0);
            acc[3][0] = __builtin_amdgcn_mfma_f32_16x16x32_bf16(a3, c0, acc[3][0], 0, 0, 0);
            acc[3][1] = __builtin_amdgcn_mfma_f32_16x16x32_bf16(a3, c1, acc[3][1], 0, 0, 0);
            __builtin_amdgcn_s_setprio(0);
            wq += 1024;
        }

#pragma unroll
        for (int n = 0; n < 2; ++n) {
            int oc = ocB * 32 + n * 16 + l15;
#pragma unroll
            for (int m = 0; m < 4; ++m) {
                int y = ty0 + w * 2 + (m >> 1);
                if (y >= 100) continue;
                int x0 = tx0 + (m & 1) * 16 + lhi * 4;
#pragma unroll
                for (int i = 0; i < 4; ++i) {
                    int x = x0 + i;
                    if (x >= 100) continue;
                    Bn[((size_t)((b * 100 + y) * 100 + x)) * 192 + oc] =
                        f2bf(fmaxf(acc[m][n][i] + bs[n], 0.f));
                }
            }
        }
    }
}

// ---------------- K3: main MFMA conv (EXACT round-7/10 kernel) ----------------
#define MFMA16(A0, A1, A2, A3, B0, B1, B2, B3)                                          \
    {                                                                                   \
        __builtin_amdgcn_s_setprio(1);                                                  \
        acc[0][0] = __builtin_amdgcn_mfma_f32_16x16x32_bf16(A0, B0, acc[0][0], 0, 0, 0);\
        acc[0][1] = __builtin_amdgcn_mfma_f32_16x16x32_bf16(A0, B1, acc[0][1], 0, 0, 0);\
        acc[0][2] = __builtin_amdgcn_mfma_f32_16x16x32_bf16(A0, B2, acc[0][2], 0, 0, 0);\
        acc[0][3] = __builtin_amdgcn_mfma_f32_16x16x32_bf16(A0, B3, acc[0][3], 0, 0, 0);\
        acc[1][0] = __builtin_amdgcn_mfma_f32_16x16x32_bf16(A1, B0, acc[1][0], 0, 0, 0);\
        acc[1][1] = __builtin_amdgcn_mfma_f32_16x16x32_bf16(A1, B1, acc[1][1], 0, 0, 0);\
        acc[1][2] = __builtin_amdgcn_mfma_f32_16x16x32_bf16(A1, B2, acc[1][2], 0, 0, 0);\
        acc[1][3] = __builtin_amdgcn_mfma_f32_16x16x32_bf16(A1, B3, acc[1][3], 0, 0, 0);\
        acc[2][0] = __builtin_amdgcn_mfma_f32_16x16x32_bf16(A2, B0, acc[2][0], 0, 0, 0);\
        acc[2][1] = __builtin_amdgcn_mfma_f32_16x16x32_bf16(A2, B1, acc[2][1], 0, 0, 0);\
        acc[2][2] = __builtin_amdgcn_mfma_f32_16x16x32_bf16(A2, B2, acc[2][2], 0, 0, 0);\
        acc[2][3] = __builtin_amdgcn_mfma_f32_16x16x32_bf16(A2, B3, acc[2][3], 0, 0, 0);\
        acc[3][0] = __builtin_amdgcn_mfma_f32_16x16x32_bf16(A3, B0, acc[3][0], 0, 0, 0);\
        acc[3][1] = __builtin_amdgcn_mfma_f32_16x16x32_bf16(A3, B1, acc[3][1], 0, 0, 0);\
        acc[3][2] = __builtin_amdgcn_mfma_f32_16x16x32_bf16(A3, B2, acc[3][2], 0, 0, 0);\
        acc[3][3] = __builtin_amdgcn_mfma_f32_16x16x32_bf16(A3, B3, acc[3][3], 0, 0, 0);\
        __builtin_amdgcn_s_setprio(0);                                                  \
    }

__global__ __launch_bounds__(256, 2) void conv_mfma_kernel(
    const unsigned short* __restrict__ Pn, const unsigned short* __restrict__ Bn,
    const unsigned short* __restrict__ Wp, const float* __restrict__ b1,
    const float* __restrict__ b2b, float* __restrict__ out) {
    __shared__ __align__(16) unsigned short sHalo[2 * HBUF];  // 73,728 B

    const int tid  = threadIdx.x;
    const int lane = tid & 63, w = tid >> 6;
    const int l15  = lane & 15, lhi = lane >> 4;
    const int ocB  = blockIdx.y;
    const int pb   = blockIdx.x;
    const int b    = pb / 36;
    const int t36  = pb % 36;
    const int ty0  = (t36 / 3) * 8;
    const int tx0  = (t36 % 3) * 32;

    const int vA = (lhi * HSLOT + w * 72 + l15) * 8;

    auto stageA = [&](int cc, int par) {
        unsigned short* dst0 = &sHalo[par * HBUF + w * HSLOT * 8];
        for (int L2 = 0; L2 < 7; ++L2) {
            int p = L2 * 64 + lane;
            if (p >= 432) p = 0;
            int hy = (p * 58255) >> 21, hx = p - hy * 36;
            gload16(Bn + ((size_t)((b * 100 + ty0 + hy) * 100 + tx0 + hx)) * 192 +
                        cc * 32 + w * 8,
                    dst0 + L2 * 512);
        }
    };
    auto stageB = [&](int seg, int par) {
        int cx = tx0 + (seg == 7 ? 5 : 0);
        unsigned short* dst0 = &sHalo[par * HBUF + w * HSLOT * 8];
        for (int L2 = 0; L2 < 9; ++L2) {
            int p = L2 * 64 + lane;
            int hy = (p * 58255) >> 21, hx = p - hy * 36;
            int gx = cx + hx;
            gx = gx > 103 ? 103 : gx;
            gload16(Pn + ((size_t)((b * 104 + ty0 + hy) * 104 + gx)) * 32 + w * 8,
                    dst0 + L2 * 512);
        }
    };

    float bb2[4], bb1[4];
#pragma unroll
    for (int n = 0; n < 4; ++n) {
        int oc  = ocB * 64 + n * 16 + l15;
        int occ = oc < 400 ? oc : 399;
        bb2[n] = b2b[occ];
        bb1[n] = b1[occ];
    }

    const unsigned short* wq = Wp + ocB * 2048 + lane * 8;
    bf16x8 c0 = *(const bf16x8*)(wq);
    bf16x8 c1 = *(const bf16x8*)(wq + 512);
    bf16x8 c2 = *(const bf16x8*)(wq + 1024);
    bf16x8 c3 = *(const bf16x8*)(wq + 1536);
    stageA(0, 0);
    __syncthreads();

    f32x4 acc[4][4] = {};
    bf16x8 a0, a1, a2, a3, q0, q1, q2, q3, n0, n1, n2, n3;

    for (int cc = 0; cc < 6; ++cc) {
        const unsigned short* hb = &sHalo[(cc & 1) * HBUF + vA];
        a0 = *(const bf16x8*)(hb);
        a1 = *(const bf16x8*)(hb + 128);
        a2 = *(const bf16x8*)(hb + 288);
        a3 = *(const bf16x8*)(hb + 416);
        if (cc < 5) stageA(cc + 1, (cc + 1) & 1);
        else        stageB(6, 0);
#pragma unroll
        for (int t = 0; t < 25; ++t) {
            wq += WST;
            n0 = *(const bf16x8*)(wq);
            n1 = *(const bf16x8*)(wq + 512);
            n2 = *(const bf16x8*)(wq + 1024);
            n3 = *(const bf16x8*)(wq + 1536);
            if (t < 24) {
                const int u = (((t + 1) / 5) * 36 + ((t + 1) % 5)) * 8;
                q0 = *(const bf16x8*)(hb + u);
                q1 = *(const bf16x8*)(hb + u + 128);
                q2 = *(const bf16x8*)(hb + u + 288);
                q3 = *(const bf16x8*)(hb + u + 416);
            }
            MFMA16(a0, a1, a2, a3, c0, c1, c2, c3);
            c0 = n0; c1 = n1; c2 = n2; c3 = n3;
            if (t < 24) { a0 = q0; a1 = q1; a2 = q2; a3 = q3; }
        }
        if (cc == 5) {
#pragma unroll
            for (int m = 0; m < 4; ++m)
#pragma unroll
                for (int n = 0; n < 4; ++n)
#pragma unroll
                    for (int i = 0; i < 4; ++i)
                        acc[m][n][i] = fmaxf(acc[m][n][i] + bb2[n], 0.f);
        }
        asm volatile("s_waitcnt vmcnt(4)" ::: "memory");
        asm volatile("s_barrier" ::: "memory");
    }

    {
        const unsigned short* hb = &sHalo[vA];
        a0 = *(const bf16x8*)(hb);
        a1 = *(const bf16x8*)(hb + 128);
        a2 = *(const bf16x8*)(hb + 288);
        a3 = *(const bf16x8*)(hb + 416);
        stageB(7, 1);
#pragma unroll
        for (int t = 0; t < 45; ++t) {
            wq += WST;
            n0 = *(const bf16x8*)(wq);
            n1 = *(const bf16x8*)(wq + 512);
            n2 = *(const bf16x8*)(wq + 1024);
            n3 = *(const bf16x8*)(wq + 1536);
            if (t < 44) {
                const int u = (((t + 1) / 5) * 36 + ((t + 1) % 5)) * 8;
                q0 = *(const bf16x8*)(hb + u);
                q1 = *(const bf16x8*)(hb + u + 128);
                q2 = *(const bf16x8*)(hb + u + 288);
                q3 = *(const bf16x8*)(hb + u + 416);
            }
            MFMA16(a0, a1, a2, a3, c0, c1, c2, c3);
            c0 = n0; c1 = n1; c2 = n2; c3 = n3;
            if (t < 44) { a0 = q0; a1 = q1; a2 = q2; a3 = q3; }
        }
        asm volatile("s_waitcnt vmcnt(4)" ::: "memory");
        asm volatile("s_barrier" ::: "memory");
    }

    {
        const unsigned short* hb = &sHalo[HBUF + vA];
        a0 = *(const bf16x8*)(hb);
        a1 = *(const bf16x8*)(hb + 128);
        a2 = *(const bf16x8*)(hb + 288);
        a3 = *(const bf16x8*)(hb + 416);
#pragma unroll
        for (int t = 0; t < 36; ++t) {
            if (t < 35) {
                wq += WST;
                n0 = *(const bf16x8*)(wq);
                n1 = *(const bf16x8*)(wq + 512);
                n2 = *(const bf16x8*)(wq + 1024);
                n3 = *(const bf16x8*)(wq + 1536);
                const int u = (((t + 1) / 4) * 36 + ((t + 1) % 4)) * 8;
                q0 = *(const bf16x8*)(hb + u);
                q1 = *(const bf16x8*)(hb + u + 128);
                q2 = *(const bf16x8*)(hb + u + 288);
                q3 = *(const bf16x8*)(hb + u + 416);
            }
            MFMA16(a0, a1, a2, a3, c0, c1, c2, c3);
            if (t < 35) { a0 = q0; a1 = q1; a2 = q2; a3 = q3;
                          c0 = n0; c1 = n1; c2 = n2; c3 = n3; }
        }
    }

#pragma unroll
    for (int n = 0; n < 4; ++n) {
        int oc = ocB * 64 + n * 16 + l15;
        if (oc >= 400) continue;
        float bv = bb1[n];
        int c25 = oc >> 4, r1 = (oc >> 2) & 3, r2 = oc & 3;
#pragma unroll
        for (int m = 0; m < 4; ++m) {
            int y  = ty0 + w * 2 + (m >> 1);
            int x0 = tx0 + (m & 1) * 16 + lhi * 4;
#pragma unroll
            for (int i = 0; i < 4; ++i) {
                out[((size_t)(b * 25 + c25) * 384 + y * 4 + r1) * 384 + (x0 + i) * 4 + r2] =
                    (acc[m][n][i] + bv) * 0.5f;
            }
        }
    }
}

extern "C" void kernel_launch(void* const* d_in, const int* in_sizes, int n_in,
                              void* d_out, int out_size, void* d_ws, size_t ws_size,
                              hipStream_t stream) {
    const float* pic = (const float*)d_in[0];
    const float* w1  = (const float*)d_in[1];
    const float* b1  = (const float*)d_in[2];
    const float* w2a = (const float*)d_in[3];
    const float* b2a = (const float*)d_in[4];
    const float* w2b = (const float*)d_in[5];
    const float* b2b = (const float*)d_in[6];
    float* out = (float*)d_out;

    char* ws = (char*)d_ws;
    unsigned short* Pn  = (unsigned short*)(ws);              // 1,384,448 B
    unsigned short* Bn  = (unsigned short*)(ws + 1384448);    // 7,680,000 B
    unsigned short* Wp  = (unsigned short*)(ws + 9064448);    // 6,623,232 B
    unsigned short* Wc2 = (unsigned short*)(ws + 15687680);   //   307,200 B

    prep1_kernel<<<91, 256, 0, stream>>>(pic, w2a, Pn, Wc2);
    conv2a_fused_kernel<<<687, 256, 0, stream>>>(Pn, Wc2, b2a, w1, w2b, Bn, Wp);
    conv_mfma_kernel<<<dim3(72, 7), 256, 0, stream>>>(Pn, Bn, Wp, b1, b2b, out);
}

// Round 12
// 149.448 us; speedup vs baseline: 1.0665x; 1.0665x over previous
//
#include <hip/hip_runtime.h>
#include <hip/hip_bf16.h>

// ---------------------------------------------------------------------------
// DimNet via bf16 MFMA implicit GEMM.
//   Pn  = padded input  NHWC bf16 [2][104][104][32]
//   Bn  = relu(conv2a)  NHWC bf16 [2][100][100][192] (g' = uv*20+mc)
//   Wp  = packed main weights [231 steps][ocb7][frag4][lane64][8] bf16
//         (+2 steps of pad for depth-2 prefetch over-read)
//   Wc2 = packed conv2a weights [ocb6][tap25][slot128][8] bf16
// prep_fused: round-10 exact (pad + w2b/w1 transposes + conv2a pack).
// conv2a_mfma: round-10 exact.
// conv_mfma: round-10 structure + DEPTH-2 weight register prefetch (c/n/d)
//   to cover HBM-miss latency on the Wp stream (L2/XCD = 4MB < 6.6MB Wp).
// ---------------------------------------------------------------------------

typedef __attribute__((ext_vector_type(8))) unsigned short ushort8;
typedef __attribute__((ext_vector_type(8))) __bf16 bf16x8;
typedef __attribute__((ext_vector_type(4))) float f32x4;

#define NB 2
#define HSLOT 576             // cells per k-slot (16 rows x 36 cols)
#define HBUF (4 * HSLOT * 8)  // ushorts per halo buffer = 18432
#define WST 14336             // ushorts per step in packed weights (7*4*64*8)

static __device__ __forceinline__ unsigned short f2bf(float f) {
    __hip_bfloat16 h = __float2bfloat16(f);
    return *reinterpret_cast<unsigned short*>(&h);
}
static __device__ __forceinline__ void gload16(const unsigned short* g, unsigned short* l) {
    __builtin_amdgcn_global_load_lds(
        (const __attribute__((address_space(1))) unsigned int*)(const void*)g,
        (__attribute__((address_space(3))) unsigned int*)(void*)l, 16, 0, 0);
}

// ---------------- fused prep: pad + weight transposes + conv2a pack ----------------
__global__ __launch_bounds__(256) void prep_fused_kernel(
    const float* __restrict__ pic, const float* __restrict__ w1,
    const float* __restrict__ w2a, const float* __restrict__ w2b,
    unsigned short* __restrict__ Pn, unsigned short* __restrict__ Wp,
    unsigned short* __restrict__ Wc2) {
    __shared__ unsigned short sT[28544];  // stride-33 staging (57KB)
    const int blk = blockIdx.x;
    const int tid = threadIdx.x;

    if (blk < 85) {
        // ---- pad: pic -> Pn NHWC bf16 ----
        int idx = blk * 256 + tid;
        if (idx >= NB * 104 * 104) return;
        int x = idx % 104;
        int y = (idx / 104) % 104;
        int b = idx / (104 * 104);
        unsigned short vals[32];
        bool inter = (y >= 4 && y < 100 && x >= 4 && x < 100);
#pragma unroll
        for (int c = 0; c < 25; ++c) {
            float v = inter ? pic[((b * 25 + c) * 96 + (y - 4)) * 96 + (x - 4)] : 0.5f;
            vals[c] = f2bf(v);
        }
#pragma unroll
        for (int c = 25; c < 32; ++c) vals[c] = 0;
        ushort8* dst = (ushort8*)(Pn + idx * 32);
#pragma unroll
        for (int j = 0; j < 4; ++j) dst[j] = *(ushort8*)&vals[j * 8];
    } else if (blk < 127) {
        // ---- w2b transpose: block (ocB, cc), two 32-oc passes ----
        int b2 = blk - 85;
        int ocB = b2 % 7, cc = b2 / 7;
        for (int n32 = 0; n32 < 2; ++n32) {
            for (int j = 0; j < 4; ++j) {
                int p  = tid * 4 + j;
                int gl = p >> 5, ol = p & 31;
                int oc = ocB * 64 + n32 * 32 + ol;
                int gp = cc * 32 + gl;
                const float* src = nullptr;
                if (oc < 400 && gp < 180) {
                    int mc = gp % 20, uv = gp / 20;      // g' = uv*20 + mc
                    src = w2b + oc * 4500 + (mc * 9 + uv) * 25;
                }
#pragma unroll
                for (int tap = 0; tap < 25; ++tap)
                    sT[(gl * 25 + tap) * 33 + ol] = src ? f2bf(src[tap]) : (unsigned short)0;
            }
            __syncthreads();
            for (int i = 0; i < 13; ++i) {
                int sid = i * 256 + tid;
                if (sid < 3200) {
                    int tap = sid >> 7;
                    int r   = sid & 127;
                    int nb = r >> 6, lane = r & 63;
                    int kq = lane >> 4;
                    int olw = nb * 16 + (lane & 15);
                    unsigned short v8[8];
#pragma unroll
                    for (int e = 0; e < 8; ++e)
                        v8[e] = sT[((kq * 8 + e) * 25 + tap) * 33 + olw];
                    size_t d = (size_t)(cc * 25 + tap) * WST + ocB * 2048 +
                               (n32 * 2 + nb) * 512 + lane * 8;
                    *(ushort8*)(Wp + d) = *(ushort8*)v8;
                }
            }
            __syncthreads();
        }
    } else if (blk < 148) {
        // ---- w1 transpose: block (ocB, tap-third), two 32-oc passes ----
        int b3 = blk - 127;
        int ocB = b3 % 7, tt = b3 / 7;   // tt 0..2, 27 linear taps each
        for (int n32 = 0; n32 < 2; ++n32) {
            for (int j = 0; j < 4; ++j) {
                int p  = tid * 4 + j;
                int cl = p >> 5, ol = p & 31;
                int oc = ocB * 64 + n32 * 32 + ol;
                const float* src = (oc < 400 && cl < 25)
                                       ? (w1 + oc * 2025 + cl * 81 + tt * 27) : nullptr;
#pragma unroll
                for (int tl = 0; tl < 27; ++tl)
                    sT[(cl * 27 + tl) * 33 + ol] = src ? f2bf(src[tl]) : (unsigned short)0;
            }
            __syncthreads();
            for (int i = 0; i < 14; ++i) {
                int sid = i * 256 + tid;
                if (sid < 3456) {
                    int tl = sid >> 7;
                    int r  = sid & 127;
                    int nb = r >> 6, lane = r & 63;
                    int kq = lane >> 4;
                    int olw = nb * 16 + (lane & 15);
                    unsigned short v8[8];
#pragma unroll
                    for (int e = 0; e < 8; ++e)
                        v8[e] = sT[((kq * 8 + e) * 27 + tl) * 33 + olw];
                    int tap_lin = tt * 27 + tl;
                    int dy = tap_lin / 9, dx = tap_lin % 9;
                    int tp = (dx < 5) ? (dy * 5 + dx) : (45 + dy * 4 + (dx - 5));
                    size_t d = (size_t)(150 + tp) * WST + ocB * 2048 +
                               (n32 * 2 + nb) * 512 + lane * 8;
                    *(ushort8*)(Wp + d) = *(ushort8*)v8;
                }
            }
            __syncthreads();
        }
    } else if (blk < 154) {
        // ---- conv2a weight pack: block = ocB2 (32 oc), threads 0..127 ----
        int ocB2 = blk - 148;
        if (tid < 128) {
            int lane = tid & 63;
            int oc = ocB2 * 32 + (tid >> 6) * 16 + (lane & 15);
            int kb = (lane >> 4) * 8;
            int uv = oc / 20, mc = oc % 20;
            int u = uv / 3, v = uv % 3;
            const float* wb[8];
#pragma unroll
            for (int e = 0; e < 8; ++e) {
                int k  = kb + e;
                int c1 = k / 5, c2 = k % 5;
                int da1 = c1 - u, da2 = c2 - v;
                bool valid = (oc < 180) && ((unsigned)da1 < 3u) && ((unsigned)da2 < 3u);
                wb[e] = valid ? (w2a + mc * 225 + (da1 * 3 + da2) * 25) : (const float*)0;
            }
            for (int tap = 0; tap < 25; ++tap) {
                unsigned short fr[8];
#pragma unroll
                for (int e = 0; e < 8; ++e) fr[e] = wb[e] ? f2bf(wb[e][tap]) : (unsigned short)0;
                *(ushort8*)(Wc2 + ((size_t)(ocB2 * 25 + tap) * 128 + tid) * 8) = *(ushort8*)fr;
            }
        }
    }
}

// ---------------- conv2a via MFMA: 256px x 32oc, packed weights ----------------
__global__ __launch_bounds__(256) void conv2a_mfma_kernel(
    const unsigned short* __restrict__ Pn, const unsigned short* __restrict__ Wc2,
    const float* __restrict__ b2a, unsigned short* __restrict__ Bn) {
    __shared__ __align__(16) unsigned short sHalo[4 * 448 * 8];  // 28,672 B

    const int tid  = threadIdx.x;
    const int lane = tid & 63, w = tid >> 6;
    const int l15  = lane & 15, lhi = lane >> 4;
    const int gx0  = blockIdx.x;          // 0..103
    const int b    = gx0 / 52, t52 = gx0 % 52;
    const int ty0  = (t52 >> 2) * 8;
    const int tx0  = (t52 & 3) * 32;
    const int ocB  = blockIdx.y;          // 0..5 (32 oc each)

    for (int L2 = 0; L2 < 7; ++L2) {
        int p = L2 * 64 + lane;
        if (p >= 432) p = 0;
        int hy = (p * 58255) >> 21, hx = p - hy * 36;
        int gy = ty0 + hy; gy = gy > 103 ? 103 : gy;
        int gx = tx0 + hx; gx = gx > 103 ? 103 : gx;
        gload16(Pn + ((size_t)((b * 104 + gy) * 104 + gx)) * 32 + w * 8,
                &sHalo[(w * 448 + L2 * 64) * 8]);
    }
    float bs[2];
#pragma unroll
    for (int n = 0; n < 2; ++n) {
        int oc = ocB * 32 + n * 16 + l15;
        bs[n] = (oc < 180) ? b2a[oc % 20] : 0.f;
    }
    __syncthreads();

    const unsigned short* hb = &sHalo[(lhi * 448 + w * 72 + l15) * 8];
    const unsigned short* wq = Wc2 + (size_t)ocB * 25600 + lane * 8;

    f32x4 acc[4][2] = {};
#pragma unroll
    for (int t = 0; t < 25; ++t) {
        const int u = ((t / 5) * 36 + (t % 5)) * 8;
        bf16x8 a0 = *(const bf16x8*)(hb + u);
        bf16x8 a1 = *(const bf16x8*)(hb + u + 128);
        bf16x8 a2 = *(const bf16x8*)(hb + u + 288);
        bf16x8 a3 = *(const bf16x8*)(hb + u + 416);
        bf16x8 c0 = *(const bf16x8*)(wq);
        bf16x8 c1 = *(const bf16x8*)(wq + 512);
        __builtin_amdgcn_s_setprio(1);
        acc[0][0] = __builtin_amdgcn_mfma_f32_16x16x32_bf16(a0, c0, acc[0][0], 0, 0, 0);
        acc[0][1] = __builtin_amdgcn_mfma_f32_16x16x32_bf16(a0, c1, acc[0][1], 0, 0, 0);
        acc[1][0] = __builtin_amdgcn_mfma_f32_16x16x32_bf16(a1, c0, acc[1][0], 0, 0, 0);
        acc[1][1] = __builtin_amdgcn_mfma_f32_16x16x32_bf16(a1, c1, acc[1][1], 0, 0, 0);
        acc[2][0] = __builtin_amdgcn_mfma_f32_16x16x32_bf16(a2, c0, acc[2][0], 0, 0, 0);
        acc[2][1] = __builtin_amdgcn_mfma_f32_16x16x32_bf16(a2, c1, acc[2][1], 0, 0, 0);
        acc[3][0] = __builtin_amdgcn_mfma_f32_16x16x32_bf16(a3, c0, acc[3][0], 0, 0, 0);
        acc[3][1] = __builtin_amdgcn_mfma_f32_16x16x32_bf16(a3, c1, acc[3][1], 0, 0, 0);
        __builtin_amdgcn_s_setprio(0);
        wq += 1024;
    }

#pragma unroll
    for (int n = 0; n < 2; ++n) {
        int oc = ocB * 32 + n * 16 + l15;
#pragma unroll
        for (int m = 0; m < 4; ++m) {
            int y = ty0 + w * 2 + (m >> 1);
            if (y >= 100) continue;
            int x0 = tx0 + (m & 1) * 16 + lhi * 4;
#pragma unroll
            for (int i = 0; i < 4; ++i) {
                int x = x0 + i;
                if (x >= 100) continue;
                Bn[((size_t)((b * 100 + y) * 100 + x)) * 192 + oc] =
                    f2bf(fmaxf(acc[m][n][i] + bs[n], 0.f));
            }
        }
    }
}

// ---------------- main MFMA conv: round-10 + depth-2 weight prefetch ----------------
#define MFMA16(A0, A1, A2, A3, B0, B1, B2, B3)                                          \
    {                                                                                   \
        __builtin_amdgcn_s_setprio(1);                                                  \
        acc[0][0] = __builtin_amdgcn_mfma_f32_16x16x32_bf16(A0, B0, acc[0][0], 0, 0, 0);\
        acc[0][1] = __builtin_amdgcn_mfma_f32_16x16x32_bf16(A0, B1, acc[0][1], 0, 0, 0);\
        acc[0][2] = __builtin_amdgcn_mfma_f32_16x16x32_bf16(A0, B2, acc[0][2], 0, 0, 0);\
        acc[0][3] = __builtin_amdgcn_mfma_f32_16x16x32_bf16(A0, B3, acc[0][3], 0, 0, 0);\
        acc[1][0] = __builtin_amdgcn_mfma_f32_16x16x32_bf16(A1, B0, acc[1][0], 0, 0, 0);\
        acc[1][1] = __builtin_amdgcn_mfma_f32_16x16x32_bf16(A1, B1, acc[1][1], 0, 0, 0);\
        acc[1][2] = __builtin_amdgcn_mfma_f32_16x16x32_bf16(A1, B2, acc[1][2], 0, 0, 0);\
        acc[1][3] = __builtin_amdgcn_mfma_f32_16x16x32_bf16(A1, B3, acc[1][3], 0, 0, 0);\
        acc[2][0] = __builtin_amdgcn_mfma_f32_16x16x32_bf16(A2, B0, acc[2][0], 0, 0, 0);\
        acc[2][1] = __builtin_amdgcn_mfma_f32_16x16x32_bf16(A2, B1, acc[2][1], 0, 0, 0);\
        acc[2][2] = __builtin_amdgcn_mfma_f32_16x16x32_bf16(A2, B2, acc[2][2], 0, 0, 0);\
        acc[2][3] = __builtin_amdgcn_mfma_f32_16x16x32_bf16(A2, B3, acc[2][3], 0, 0, 0);\
        acc[3][0] = __builtin_amdgcn_mfma_f32_16x16x32_bf16(A3, B0, acc[3][0], 0, 0, 0);\
        acc[3][1] = __builtin_amdgcn_mfma_f32_16x16x32_bf16(A3, B1, acc[3][1], 0, 0, 0);\
        acc[3][2] = __builtin_amdgcn_mfma_f32_16x16x32_bf16(A3, B2, acc[3][2], 0, 0, 0);\
        acc[3][3] = __builtin_amdgcn_mfma_f32_16x16x32_bf16(A3, B3, acc[3][3], 0, 0, 0);\
        __builtin_amdgcn_s_setprio(0);                                                  \
    }

// per-tap body: advance wq 2-ahead, load d, compute with c, rotate c<-n<-d
#define WTAP(HOFF)                                                    \
    {                                                                 \
        wq += WST;                                                    \
        bf16x8 d0 = *(const bf16x8*)(wq);                             \
        bf16x8 d1 = *(const bf16x8*)(wq + 512);                       \
        bf16x8 d2 = *(const bf16x8*)(wq + 1024);                      \
        bf16x8 d3 = *(const bf16x8*)(wq + 1536);                      \
        bf16x8 a0 = *(const bf16x8*)(hb + (HOFF));                    \
        bf16x8 a1 = *(const bf16x8*)(hb + (HOFF) + 128);              \
        bf16x8 a2 = *(const bf16x8*)(hb + (HOFF) + 288);              \
        bf16x8 a3 = *(const bf16x8*)(hb + (HOFF) + 416);              \
        MFMA16(a0, a1, a2, a3, c0, c1, c2, c3);                       \
        c0 = n0; c1 = n1; c2 = n2; c3 = n3;                           \
        n0 = d0; n1 = d1; n2 = d2; n3 = d3;                           \
    }

__global__ __launch_bounds__(256, 2) void conv_mfma_kernel(
    const unsigned short* __restrict__ Pn, const unsigned short* __restrict__ Bn,
    const unsigned short* __restrict__ Wp, const float* __restrict__ b1,
    const float* __restrict__ b2b, float* __restrict__ out) {
    __shared__ __align__(16) unsigned short sHalo[2 * HBUF];  // 73,728 B

    const int tid  = threadIdx.x;
    const int lane = tid & 63, w = tid >> 6;
    const int l15  = lane & 15, lhi = lane >> 4;
    const int ocB  = blockIdx.y;
    const int pb   = blockIdx.x;
    const int b    = pb / 36;
    const int t36  = pb % 36;
    const int ty0  = (t36 / 3) * 8;
    const int tx0  = (t36 % 3) * 32;

    const int vA = (lhi * HSLOT + w * 72 + l15) * 8;

    auto stageA = [&](int cc, int par) {
        unsigned short* dst0 = &sHalo[par * HBUF + w * HSLOT * 8];
        for (int L2 = 0; L2 < 7; ++L2) {
            int p = L2 * 64 + lane;
            if (p >= 432) p = 0;
            int hy = (p * 58255) >> 21, hx = p - hy * 36;
            gload16(Bn + ((size_t)((b * 100 + ty0 + hy) * 100 + tx0 + hx)) * 192 +
                        cc * 32 + w * 8,
                    dst0 + L2 * 512);
        }
    };
    auto stageB = [&](int seg, int par) {
        int cx = tx0 + (seg == 7 ? 5 : 0);
        unsigned short* dst0 = &sHalo[par * HBUF + w * HSLOT * 8];
        for (int L2 = 0; L2 < 9; ++L2) {
            int p = L2 * 64 + lane;
            int hy = (p * 58255) >> 21, hx = p - hy * 36;
            int gx = cx + hx;
            gx = gx > 103 ? 103 : gx;
            gload16(Pn + ((size_t)((b * 104 + ty0 + hy) * 104 + gx)) * 32 + w * 8,
                    dst0 + L2 * 512);
        }
    };

    float bb2[4], bb1[4];
#pragma unroll
    for (int n = 0; n < 4; ++n) {
        int oc  = ocB * 64 + n * 16 + l15;
        int occ = oc < 400 ? oc : 399;
        bb2[n] = b2b[occ];
        bb1[n] = b1[occ];
    }

    // depth-2 weight pipeline: c = step s, n = step s+1, wq -> step s+1
    const unsigned short* wq = Wp + ocB * 2048 + lane * 8;
    bf16x8 c0 = *(const bf16x8*)(wq);
    bf16x8 c1 = *(const bf16x8*)(wq + 512);
    bf16x8 c2 = *(const bf16x8*)(wq + 1024);
    bf16x8 c3 = *(const bf16x8*)(wq + 1536);
    bf16x8 n0 = *(const bf16x8*)(wq + WST);
    bf16x8 n1 = *(const bf16x8*)(wq + WST + 512);
    bf16x8 n2 = *(const bf16x8*)(wq + WST + 1024);
    bf16x8 n3 = *(const bf16x8*)(wq + WST + 1536);
    wq += WST;
    stageA(0, 0);
    __syncthreads();

    f32x4 acc[4][4] = {};

    // -------- phase A: 6 segments x 25 taps --------
    for (int cc = 0; cc < 6; ++cc) {
        const unsigned short* hb = &sHalo[(cc & 1) * HBUF + vA];
        if (cc < 5) stageA(cc + 1, (cc + 1) & 1);
        else        stageB(6, 0);
#pragma unroll
        for (int t = 0; t < 25; ++t)
            WTAP(((t / 5) * 36 + (t % 5)) * 8);
        if (cc == 5) {  // p2 = relu(p2 + b2b)
#pragma unroll
            for (int m = 0; m < 4; ++m)
#pragma unroll
                for (int n = 0; n < 4; ++n)
#pragma unroll
                    for (int i = 0; i < 4; ++i)
                        acc[m][n][i] = fmaxf(acc[m][n][i] + bb2[n], 0.f);
        }
        asm volatile("s_waitcnt vmcnt(8)" ::: "memory");
        asm volatile("s_barrier" ::: "memory");
    }

    // -------- phase B1: 45 taps (dy 0..8, dx 0..4), halo parity 0 --------
    {
        const unsigned short* hb = &sHalo[vA];
        stageB(7, 1);
#pragma unroll
        for (int t = 0; t < 45; ++t)
            WTAP(((t / 5) * 36 + (t % 5)) * 8);
        asm volatile("s_waitcnt vmcnt(8)" ::: "memory");
        asm volatile("s_barrier" ::: "memory");
    }

    // -------- phase B2: 36 taps (dy 0..8, dx 5..8), halo parity 1 --------
    {
        const unsigned short* hb = &sHalo[HBUF + vA];
#pragma unroll
        for (int t = 0; t < 36; ++t)
            WTAP(((t >> 2) * 36 + (t & 3)) * 8);  // over-reads land in Wp pad
    }

    // -------- epilogue: (p1+p2+b1)/2, pixel-shuffled --------
#pragma unroll
    for (int n = 0; n < 4; ++n) {
        int oc = ocB * 64 + n * 16 + l15;
        if (oc >= 400) continue;
        float bv = bb1[n];
        int c25 = oc >> 4, r1 = (oc >> 2) & 3, r2 = oc & 3;
#pragma unroll
        for (int m = 0; m < 4; ++m) {
            int y  = ty0 + w * 2 + (m >> 1);
            int x0 = tx0 + (m & 1) * 16 + lhi * 4;
#pragma unroll
            for (int i = 0; i < 4; ++i) {
                out[((size_t)(b * 25 + c25) * 384 + y * 4 + r1) * 384 + (x0 + i) * 4 + r2] =
                    (acc[m][n][i] + bv) * 0.5f;
            }
        }
    }
}

extern "C" void kernel_launch(void* const* d_in, const int* in_sizes, int n_in,
                              void* d_out, int out_size, void* d_ws, size_t ws_size,
                              hipStream_t stream) {
    const float* pic = (const float*)d_in[0];
    const float* w1  = (const float*)d_in[1];
    const float* b1  = (const float*)d_in[2];
    const float* w2a = (const float*)d_in[3];
    const float* b2a = (const float*)d_in[4];
    const float* w2b = (const float*)d_in[5];
    const float* b2b = (const float*)d_in[6];
    float* out = (float*)d_out;

    char* ws = (char*)d_ws;
    unsigned short* Pn  = (unsigned short*)(ws);              // 1,384,448 B
    unsigned short* Bn  = (unsigned short*)(ws + 1384448);    // 7,680,000 B
    unsigned short* Wp  = (unsigned short*)(ws + 9064448);    // 6,623,232 B (+57,344 pad)
    unsigned short* Wc2 = (unsigned short*)(ws + 15745024);   //   307,200 B  (tot 16.05MB)

    prep_fused_kernel<<<154, 256, 0, stream>>>(pic, w1, w2a, w2b, Pn, Wp, Wc2);
    conv2a_mfma_kernel<<<dim3(104, 6), 256, 0, stream>>>(Pn, Wc2, b2a, Bn);
    conv_mfma_kernel<<<dim3(72, 7), 256, 0, stream>>>(Pn, Bn, Wp, b1, b2b, out);
}